// Round 2
// baseline (1166.501 us; speedup 1.0000x reference)
//
#include <hip/hip_runtime.h>
#include <stdint.h>

typedef unsigned short u16;
typedef __bf16 bf16x8 __attribute__((ext_vector_type(8)));
typedef float f32x4 __attribute__((ext_vector_type(4)));

#define T_TOK 8192      // B*S tokens
#define DM    1024      // d_model
#define DF    4096      // d_ff
#define NE    8         // experts
#define BM2   256       // GEMM tile M and N (8-phase 256^2 template)
#define BK    64        // GEMM tile K (bf16 elems)
#define BUFE  (BM2*BK)  // 16384 elems = 32KB per operand per buffer
#define MAXT2 72        // max 256-row tiles: 16384/256 + NE

// ---- helpers ----------------------------------------------------------------

__device__ __forceinline__ u16 f2b(float f) {   // fp32 -> bf16 RNE
  union { float f; uint32_t u; } v; v.f = f;
  uint32_t r = (v.u + 0x7FFFu + ((v.u >> 16) & 1u)) >> 16;
  return (u16)r;
}

__device__ __forceinline__ void async16(const void* g, void* l) {
  // 16B/lane global->LDS DMA; LDS dest = wave-uniform base + lane*16
  __builtin_amdgcn_global_load_lds((const __attribute__((address_space(1))) void*)g,
                                   (__attribute__((address_space(3))) void*)l, 16, 0, 0);
}

// Single-path erf-based gelu (A&S 7.1.26, |err|<1.5e-7 in erf).
__device__ __forceinline__ float fast_gelu(float v) {
  float x = v * 0.70710678118654752f;
  float a = fabsf(x);
  float t = __builtin_amdgcn_rcpf(fmaf(0.3275911f, a, 1.0f));
  float p = t * fmaf(t, fmaf(t, fmaf(t, fmaf(t, 1.061405429f, -1.453152027f),
                                     1.421413741f), -0.284496736f), 0.254829592f);
  float e = __expf(-a * a);
  float erf_a = fmaf(-p, e, 1.0f);
  float erf_x = (x < 0.f) ? -erf_a : erf_a;
  return 0.5f * v * (1.0f + erf_x);
}

// ---- router: logits, top-2 softmax weights, bucket append, x->bf16 ----------

__global__ __launch_bounds__(256) void router_k(
    const float* __restrict__ x, const float* __restrict__ rw,
    const float* __restrict__ rb, u16* __restrict__ xb,
    float* __restrict__ wsl, int* __restrict__ bucket, int* __restrict__ counts)
{
  int lane = threadIdx.x & 63;
  int t = blockIdx.x * 4 + (threadIdx.x >> 6);   // one wave per token
  const float* xp = x + (size_t)t * DM;
  float acc[NE];
#pragma unroll
  for (int e = 0; e < NE; ++e) acc[e] = 0.f;
  for (int i = 0; i < DM / 64; ++i) {
    int idx = i * 64 + lane;
    float xv = xp[idx];
    xb[(size_t)t * DM + idx] = f2b(xv);          // fused x -> bf16
#pragma unroll
    for (int e = 0; e < NE; ++e) acc[e] += xv * rw[e * DM + idx];
  }
#pragma unroll
  for (int e = 0; e < NE; ++e) {
#pragma unroll
    for (int off = 32; off >= 1; off >>= 1) acc[e] += __shfl_xor(acc[e], off);
  }
  if (lane == 0) {
    float l[NE];
#pragma unroll
    for (int e = 0; e < NE; ++e) l[e] = acc[e] + rb[e];
    int i1 = 0;
#pragma unroll
    for (int e = 1; e < NE; ++e) if (l[e] > l[i1]) i1 = e;   // strict > : lowest idx on tie
    int i2 = (i1 == 0) ? 1 : 0;
#pragma unroll
    for (int e = 0; e < NE; ++e) if (e != i1 && l[e] > l[i2]) i2 = e;
    float e2 = expf(l[i2] - l[i1]);
    float wa = 1.f / (1.f + e2);
    wsl[2 * t]     = wa;
    wsl[2 * t + 1] = 1.f - wa;
    int p1 = atomicAdd(&counts[i1], 1); bucket[i1 * T_TOK + p1] = 2 * t;
    int p2 = atomicAdd(&counts[i2], 1); bucket[i2 * T_TOK + p2] = 2 * t + 1;
  }
}

// ---- fp32 -> bf16 weight convert -------------------------------------------

struct alignas(8) U16x4 { u16 x, y, z, w; };

__global__ __launch_bounds__(256) void cvt_k(const float* __restrict__ w,
                                             u16* __restrict__ o)
{
  int i = blockIdx.x * 256 + threadIdx.x;
  float4 v = ((const float4*)w)[i];
  U16x4 u; u.x = f2b(v.x); u.y = f2b(v.y); u.z = f2b(v.z); u.w = f2b(v.w);
  ((U16x4*)o)[i] = u;
}

// ---- tile prefix (256-row tiles) --------------------------------------------

__global__ void toff_k(const int* __restrict__ counts, int* __restrict__ toff) {
  if (threadIdx.x == 0 && blockIdx.x == 0) {
    int a = 0;
    for (int e = 0; e < NE; ++e) { toff[e] = a; a += (counts[e] + BM2 - 1) >> 8; }
    toff[NE] = a;
  }
}

// ---- 8-phase 256^2 GEMM mainloop (m201 template, plain HIP) -----------------
// 8 waves (2M x 4N), per-wave output 128x64. Double-buffered A/B (BK=64).
// Per iteration: 2 K-tiles, 8 phases. Each phase: {ds_read subtile | stage one
// half-tile} -> barrier -> lgkmcnt(0) -> setprio(1) 16 MFMA setprio(0) ->
// [vmcnt(4) at p4/p8] -> barrier. Counted vmcnt keeps 2-6 half-tile loads in
// flight across barriers; vmcnt(4) at p4/p8 guarantees the tile about to be
// read (staged 4-6 phases earlier) has landed.
// LDS XOR-swizzle (T2): physical 16B-chunk p of row r holds logical chunk
// p ^ (r&7); staging pre-swizzles the *global* source offset (linear LDS dest,
// required by global_load_lds), reads XOR on the ds_read side.

#define STG_A(buf,h,p0,p1,koff) do{ \
  async16((p0) + (koff), sA + (buf)*BUFE + ((h)*128)*BK + tid*8); \
  async16((p1) + (koff), sA + (buf)*BUFE + ((h)*128+64)*BK + tid*8); }while(0)

#define STG_B(buf,h,koff) do{ \
  async16(bb + (size_t)((h)*128)*KD + (koff), sB + (buf)*BUFE + ((h)*128)*BK + tid*8); \
  async16(bb + (size_t)((h)*128+64)*KD + (koff), sB + (buf)*BUFE + ((h)*128+64)*BK + tid*8); }while(0)

#define LD_A(buf,hb) do{ \
  _Pragma("unroll") for (int m = 0; m < 4; ++m) { \
    int row_ = wm*128 + (hb)*64 + m*16 + l15; \
    const u16* base_ = sA + (buf)*BUFE + row_*BK; \
    _Pragma("unroll") for (int kk = 0; kk < 2; ++kk) \
      af[m*2+kk] = *(const bf16x8*)(base_ + (((kk*4+ch) ^ (row_ & 7)) << 3)); \
  } }while(0)

#define LD_B(buf,nh) do{ \
  _Pragma("unroll") for (int n = 0; n < 2; ++n) { \
    int row_ = wn*64 + ((nh)*2+n)*16 + l15; \
    const u16* base_ = sB + (buf)*BUFE + row_*BK; \
    _Pragma("unroll") for (int kk = 0; kk < 2; ++kk) \
      bf[((nh)*2+n)*2+kk] = *(const bf16x8*)(base_ + (((kk*4+ch) ^ (row_ & 7)) << 3)); \
  } }while(0)

#define MM(mh,nh) do{ \
  _Pragma("unroll") for (int m = 0; m < 4; ++m) \
  _Pragma("unroll") for (int n = 0; n < 2; ++n) { \
    f32x4 c_ = acc[(mh)*4+m][(nh)*2+n]; \
    c_ = __builtin_amdgcn_mfma_f32_16x16x32_bf16(af[m*2+0], bf[((nh)*2+n)*2+0], c_, 0,0,0); \
    c_ = __builtin_amdgcn_mfma_f32_16x16x32_bf16(af[m*2+1], bf[((nh)*2+n)*2+1], c_, 0,0,0); \
    acc[(mh)*4+m][(nh)*2+n] = c_; } }while(0)

#define PH_MID() do{ __builtin_amdgcn_s_barrier(); \
  asm volatile("s_waitcnt lgkmcnt(0)":::"memory"); \
  __builtin_amdgcn_sched_barrier(0); \
  __builtin_amdgcn_s_setprio(1); }while(0)

#define PH_END() do{ __builtin_amdgcn_s_setprio(0); \
  __builtin_amdgcn_s_barrier(); }while(0)

#define PH_END_VM4() do{ __builtin_amdgcn_s_setprio(0); \
  asm volatile("s_waitcnt vmcnt(4)":::"memory"); \
  __builtin_amdgcn_sched_barrier(0); \
  __builtin_amdgcn_s_barrier(); }while(0)

#define PH_END_VM0() do{ __builtin_amdgcn_s_setprio(0); \
  asm volatile("s_waitcnt vmcnt(0)":::"memory"); \
  __builtin_amdgcn_sched_barrier(0); \
  __builtin_amdgcn_s_barrier(); }while(0)

template<int KD, int NITER>
__device__ __forceinline__ void gemm8(
    u16* sA, u16* sB,
    const u16* a0, const u16* a1, const u16* a2, const u16* a3,
    const u16* bb, int tid, f32x4 (&acc)[8][4])
{
  const int lane = tid & 63;
  const int wid  = tid >> 6;
  const int wm = wid >> 2, wn = wid & 3;   // 2M x 4N waves
  const int l15 = lane & 15;
  const int ch  = lane >> 4;
  bf16x8 af[8], bf[8];

  // prologue: tile0 (A+B) + tile1 B halves; drain tile0, leave tile1-B in flight
  STG_A(0,0,a0,a1,0); STG_A(0,1,a2,a3,0);
  STG_B(0,0,0);       STG_B(0,1,0);
  STG_B(1,0,64);      STG_B(1,1,64);
  asm volatile("s_waitcnt vmcnt(4)":::"memory");
  __builtin_amdgcn_sched_barrier(0);
  __builtin_amdgcn_s_barrier();

#pragma unroll 1
  for (int t = 0; t < NITER - 1; ++t) {
    // p1: q00 of buf0 | stage A-h0(tile 2t+1)
    LD_A(0,0); LD_B(0,0); STG_A(1,0,a0,a1,64);
    PH_MID(); MM(0,0); PH_END();
    // p2: q01 | stage A-h1(2t+1)
    LD_B(0,1); STG_A(1,1,a2,a3,64);
    PH_MID(); MM(0,1); PH_END();
    // p3: q10 | stage B-h0(2t+2)
    LD_A(0,1); STG_B(0,0,128);
    PH_MID(); MM(1,0); PH_END();
    // p4: q11 | stage B-h1(2t+2); checkpoint: tile 2t+1 landed
    STG_B(0,1,128);
    PH_MID(); MM(1,1); PH_END_VM4();
    // p5: q00 of buf1 | stage A-h0(2t+2)
    LD_A(1,0); LD_B(1,0); STG_A(0,0,a0,a1,128);
    PH_MID(); MM(0,0); PH_END();
    // p6: q01 | stage A-h1(2t+2)
    LD_B(1,1); STG_A(0,1,a2,a3,128);
    PH_MID(); MM(0,1); PH_END();
    // p7: q10 | stage B-h0(2t+3)
    LD_A(1,1); STG_B(1,0,192);
    PH_MID(); MM(1,0); PH_END();
    // p8: q11 | stage B-h1(2t+3); checkpoint: tile 2t+2 landed
    STG_B(1,1,192);
    PH_MID(); MM(1,1); PH_END_VM4();
    a0 += 2*BK; a1 += 2*BK; a2 += 2*BK; a3 += 2*BK; bb += 2*BK;
  }
  // final iteration: stage only A of last tile; vmcnt(0) before reading it
  LD_A(0,0); LD_B(0,0); STG_A(1,0,a0,a1,64);
  PH_MID(); MM(0,0); PH_END();
  LD_B(0,1); STG_A(1,1,a2,a3,64);
  PH_MID(); MM(0,1); PH_END();
  LD_A(0,1);
  PH_MID(); MM(1,0); PH_END();
  PH_MID(); MM(1,1); PH_END_VM0();
  LD_A(1,0); LD_B(1,0);
  PH_MID(); MM(0,0); PH_END();
  LD_B(1,1);
  PH_MID(); MM(0,1); PH_END();
  LD_A(1,1);
  PH_MID(); MM(1,0); PH_END();
  PH_MID(); MM(1,1);
  __builtin_amdgcn_s_setprio(0);
}

// ---- stage 1: H[slot, DF] = gelu( gather(xb) @ w1[e]^T + b1[e] ) ------------
// grid (DF/256 = 16, MAXT2), 512 threads; XCD-chunked bijective swizzle.

__global__ __launch_bounds__(512, 2) void stage1_k(
    const u16* __restrict__ xb, const u16* __restrict__ w1b,
    const float* __restrict__ b1, const int* __restrict__ bucket,
    const int* __restrict__ counts, const int* __restrict__ toff,
    u16* __restrict__ H)
{
  __shared__ __align__(16) u16 sA[2*BUFE];
  __shared__ __align__(16) u16 sB[2*BUFE];
  __shared__ int sSlot[BM2];

  int bid = blockIdx.y * 16 + blockIdx.x;            // nwg = 16*72 = 1152, %8==0
  int lid = (bid & 7) * (16 * MAXT2 / 8) + (bid >> 3);
  int fs = lid & 15;
  int tb = lid >> 4;
  if (tb >= toff[NE]) return;
  int e = 0;
#pragma unroll
  for (int q = 1; q < NE; ++q) if (tb >= toff[q]) e = q;
  int ti = tb - toff[e];
  int cnt = counts[e];
  int tid = threadIdx.x;

  if (tid < BM2) {
    int r = ti * BM2 + tid;
    sSlot[tid] = (r < cnt) ? bucket[e * T_TOK + r] : -1;
  }
  __syncthreads();

  int rowb = tid >> 3;
  int swz  = ((tid & 7) ^ (rowb & 7)) * 8;           // pre-swizzled global chunk
  int s0 = sSlot[0*64 + rowb], s1 = sSlot[1*64 + rowb];
  int s2 = sSlot[2*64 + rowb], s3 = sSlot[3*64 + rowb];
  const u16* a0 = xb + (size_t)((s0 < 0) ? 0 : (s0 >> 1)) * DM + swz;
  const u16* a1 = xb + (size_t)((s1 < 0) ? 0 : (s1 >> 1)) * DM + swz;
  const u16* a2 = xb + (size_t)((s2 < 0) ? 0 : (s2 >> 1)) * DM + swz;
  const u16* a3 = xb + (size_t)((s3 < 0) ? 0 : (s3 >> 1)) * DM + swz;
  const u16* bb = w1b + ((size_t)e * DF + (size_t)fs * 256 + rowb) * DM + swz;

  f32x4 acc[8][4] = {};
  gemm8<DM, DM / BK / 2>(sA, sB, a0, a1, a2, a3, bb, tid, acc);

  int lane = tid & 63, wid = tid >> 6;
  int wm = wid >> 2, wn = wid & 3;
  int l15 = lane & 15, ch = lane >> 4;
  int fbase = fs * 256;
#pragma unroll
  for (int m = 0; m < 8; ++m) {
    int mb = wm*128 + m*16 + ch*4;
#pragma unroll
    for (int n = 0; n < 4; ++n) {
      int col = wn*64 + n*16 + l15;
      float bias = b1[e * DF + fbase + col];
#pragma unroll
      for (int r = 0; r < 4; ++r) {
        int slot = sSlot[mb + r];
        if (slot >= 0) {
          float v = acc[m][n][r] + bias;
          H[(size_t)slot * DF + fbase + col] = f2b(fast_gelu(v));
        }
      }
    }
  }
}

// ---- stage 2: out[token] += w * ( gather(H) @ w2[e]^T + b2[e] ) -------------
// grid (4 col-slices x 2 K-splits = 8, MAXT2), 512 threads. Split-K=2 over
// DF: each split does K=2048 (32 tiles); bias applied by split 0 only; both
// splits atomicAdd (out is zeroed).

__global__ __launch_bounds__(512, 2) void stage2_k(
    const u16* __restrict__ H, const u16* __restrict__ w2b,
    const float* __restrict__ b2, const float* __restrict__ wsl,
    const int* __restrict__ bucket, const int* __restrict__ counts,
    const int* __restrict__ toff, float* __restrict__ out)
{
  __shared__ __align__(16) u16 sA[2*BUFE];
  __shared__ __align__(16) u16 sB[2*BUFE];
  __shared__ int sSlot[BM2];

  int bid = blockIdx.y * 8 + blockIdx.x;             // nwg = 8*72 = 576, %8==0
  int lid = (bid & 7) * (8 * MAXT2 / 8) + (bid >> 3);
  int xx = lid & 7;
  int tb = lid >> 3;
  int sl = xx & 3, sp = xx >> 2;
  if (tb >= toff[NE]) return;
  int e = 0;
#pragma unroll
  for (int q = 1; q < NE; ++q) if (tb >= toff[q]) e = q;
  int ti = tb - toff[e];
  int cnt = counts[e];
  int tid = threadIdx.x;

  if (tid < BM2) {
    int r = ti * BM2 + tid;
    sSlot[tid] = (r < cnt) ? bucket[e * T_TOK + r] : -1;
  }
  __syncthreads();

  int rowb = tid >> 3;
  int swz  = ((tid & 7) ^ (rowb & 7)) * 8;
  int kbase = sp * 2048;
  int s0 = sSlot[0*64 + rowb], s1 = sSlot[1*64 + rowb];
  int s2 = sSlot[2*64 + rowb], s3 = sSlot[3*64 + rowb];
  const u16* a0 = H + (size_t)((s0 < 0) ? 0 : s0) * DF + kbase + swz;
  const u16* a1 = H + (size_t)((s1 < 0) ? 0 : s1) * DF + kbase + swz;
  const u16* a2 = H + (size_t)((s2 < 0) ? 0 : s2) * DF + kbase + swz;
  const u16* a3 = H + (size_t)((s3 < 0) ? 0 : s3) * DF + kbase + swz;
  const u16* bb = w2b + ((size_t)e * DM + (size_t)sl * 256 + rowb) * DF + kbase + swz;

  f32x4 acc[8][4] = {};
  gemm8<DF, 2048 / BK / 2>(sA, sB, a0, a1, a2, a3, bb, tid, acc);

  int lane = tid & 63, wid = tid >> 6;
  int wm = wid >> 2, wn = wid & 3;
  int l15 = lane & 15, ch = lane >> 4;
  int dbase = sl * 256;
#pragma unroll
  for (int m = 0; m < 8; ++m) {
    int mb = wm*128 + m*16 + ch*4;
#pragma unroll
    for (int n = 0; n < 4; ++n) {
      int col = wn*64 + n*16 + l15;
      float bias = (sp == 0) ? b2[e * DM + dbase + col] : 0.f;
#pragma unroll
      for (int r = 0; r < 4; ++r) {
        int slot = sSlot[mb + r];
        if (slot >= 0) {
          float v = (acc[m][n][r] + bias) * wsl[slot];
          atomicAdd(&out[(size_t)(slot >> 1) * DM + dbase + col], v);
        }
      }
    }
  }
}

// ---- launch -----------------------------------------------------------------

extern "C" void kernel_launch(void* const* d_in, const int* in_sizes, int n_in,
                              void* d_out, int out_size, void* d_ws, size_t ws_size,
                              hipStream_t stream) {
  const float* x  = (const float*)d_in[0];
  const float* rw = (const float*)d_in[1];
  const float* rb = (const float*)d_in[2];
  const float* w1 = (const float*)d_in[3];
  const float* b1 = (const float*)d_in[4];
  const float* w2 = (const float*)d_in[5];
  const float* b2 = (const float*)d_in[6];
  float* out = (float*)d_out;

  char* ws = (char*)d_ws;
  size_t off = 0;
  auto alloc = [&](size_t bytes) -> void* {
    void* p = ws + off;
    off = (off + bytes + 255) & ~(size_t)255;
    return p;
  };
  u16*   xb     = (u16*)alloc((size_t)T_TOK * DM * 2);        // 16.8 MB
  u16*   w1b    = (u16*)alloc((size_t)NE * DF * DM * 2);      // 67.1 MB
  u16*   w2b    = (u16*)alloc((size_t)NE * DM * DF * 2);      // 67.1 MB
  u16*   H      = (u16*)alloc((size_t)(2 * T_TOK) * DF * 2);  // 134.2 MB
  float* wsl    = (float*)alloc((size_t)(2 * T_TOK) * 4);
  int*   bucket = (int*)alloc((size_t)NE * T_TOK * 4);
  int*   counts = (int*)alloc(256);
  int*   toff   = (int*)alloc(256);

  hipMemsetAsync(counts, 0, NE * sizeof(int), stream);
  hipMemsetAsync(out, 0, (size_t)out_size * sizeof(float), stream);

  router_k<<<T_TOK / 4, 256, 0, stream>>>(x, rw, rb, xb, wsl, bucket, counts);
  cvt_k<<<(NE * DF * DM) / (256 * 4), 256, 0, stream>>>(w1, w1b);
  cvt_k<<<(NE * DM * DF) / (256 * 4), 256, 0, stream>>>(w2, w2b);
  toff_k<<<1, 64, 0, stream>>>(counts, toff);
  stage1_k<<<dim3(DF / 256, MAXT2), 512, 0, stream>>>(xb, w1b, b1, bucket, counts, toff, H);
  stage2_k<<<dim3(8, MAXT2), 512, 0, stream>>>(H, w2b, b2, wsl, bucket, counts, toff, out);
}

// Round 4
// 1165.452 us; speedup vs baseline: 1.0009x; 1.0009x over previous
//
#include <hip/hip_runtime.h>
#include <stdint.h>

typedef unsigned short u16;
typedef __bf16 bf16x8 __attribute__((ext_vector_type(8)));
typedef float f32x4 __attribute__((ext_vector_type(4)));

#define T_TOK 8192      // B*S tokens
#define DM    1024      // d_model
#define DF    4096      // d_ff
#define NE    8         // experts
#define BM    128       // GEMM tile M
#define BK    64        // GEMM tile K (bf16 elems)
#define TILEE (BM*BK)   // 8192 elems = 16KB per operand per buffer
#define MAXT  136       // max total tiles: 16384/128 + NE

// ---- helpers ----------------------------------------------------------------

__device__ __forceinline__ u16 f2b(float f) {   // fp32 -> bf16 RNE
  union { float f; uint32_t u; } v; v.f = f;
  uint32_t r = (v.u + 0x7FFFu + ((v.u >> 16) & 1u)) >> 16;
  return (u16)r;
}

__device__ __forceinline__ void async16(const void* g, void* l) {
  // 16B/lane global->LDS DMA; LDS dest = wave-uniform base + lane*16
  __builtin_amdgcn_global_load_lds((const __attribute__((address_space(1))) void*)g,
                                   (__attribute__((address_space(3))) void*)l, 16, 0, 0);
}

// Single-path erf-based gelu (A&S 7.1.26, |err|<1.5e-7 in erf).
__device__ __forceinline__ float fast_gelu(float v) {
  float x = v * 0.70710678118654752f;
  float a = fabsf(x);
  float t = __builtin_amdgcn_rcpf(fmaf(0.3275911f, a, 1.0f));
  float p = t * fmaf(t, fmaf(t, fmaf(t, fmaf(t, 1.061405429f, -1.453152027f),
                                     1.421413741f), -0.284496736f), 0.254829592f);
  float e = __expf(-a * a);
  float erf_a = fmaf(-p, e, 1.0f);
  float erf_x = (x < 0.f) ? -erf_a : erf_a;
  return 0.5f * v * (1.0f + erf_x);
}

// ---- router: logits, top-2 softmax weights, bucket append, x->bf16 ----------

__global__ __launch_bounds__(256) void router_k(
    const float* __restrict__ x, const float* __restrict__ rw,
    const float* __restrict__ rb, u16* __restrict__ xb,
    float* __restrict__ wsl, int* __restrict__ bucket, int* __restrict__ counts)
{
  int lane = threadIdx.x & 63;
  int t = blockIdx.x * 4 + (threadIdx.x >> 6);   // one wave per token
  const float* xp = x + (size_t)t * DM;
  float acc[NE];
#pragma unroll
  for (int e = 0; e < NE; ++e) acc[e] = 0.f;
  for (int i = 0; i < DM / 64; ++i) {
    int idx = i * 64 + lane;
    float xv = xp[idx];
    xb[(size_t)t * DM + idx] = f2b(xv);          // fused x -> bf16
#pragma unroll
    for (int e = 0; e < NE; ++e) acc[e] += xv * rw[e * DM + idx];
  }
#pragma unroll
  for (int e = 0; e < NE; ++e) {
#pragma unroll
    for (int off = 32; off >= 1; off >>= 1) acc[e] += __shfl_xor(acc[e], off);
  }
  if (lane == 0) {
    float l[NE];
#pragma unroll
    for (int e = 0; e < NE; ++e) l[e] = acc[e] + rb[e];
    int i1 = 0;
#pragma unroll
    for (int e = 1; e < NE; ++e) if (l[e] > l[i1]) i1 = e;   // strict > : lowest idx on tie
    int i2 = (i1 == 0) ? 1 : 0;
#pragma unroll
    for (int e = 0; e < NE; ++e) if (e != i1 && l[e] > l[i2]) i2 = e;
    float e2 = expf(l[i2] - l[i1]);
    float wa = 1.f / (1.f + e2);
    wsl[2 * t]     = wa;
    wsl[2 * t + 1] = 1.f - wa;
    int p1 = atomicAdd(&counts[i1], 1); bucket[i1 * T_TOK + p1] = 2 * t;
    int p2 = atomicAdd(&counts[i2], 1); bucket[i2 * T_TOK + p2] = 2 * t + 1;
  }
}

// ---- fp32 -> bf16 weight convert (grid-stride, 2048 blocks) -----------------

struct alignas(8) U16x4 { u16 x, y, z, w; };

__global__ __launch_bounds__(256) void cvt_k(const float* __restrict__ w,
                                             u16* __restrict__ o, int n4)
{
  int stride = gridDim.x * 256;
  for (int i = blockIdx.x * 256 + threadIdx.x; i < n4; i += stride) {
    float4 v = ((const float4*)w)[i];
    U16x4 u; u.x = f2b(v.x); u.y = f2b(v.y); u.z = f2b(v.z); u.w = f2b(v.w);
    ((U16x4*)o)[i] = u;
  }
}

// ---- tile prefix (1 thread; 8 experts) --------------------------------------

__global__ void toff_k(const int* __restrict__ counts, int* __restrict__ toff) {
  if (threadIdx.x == 0 && blockIdx.x == 0) {
    int a = 0;
    for (int e = 0; e < NE; ++e) { toff[e] = a; a += (counts[e] + BM - 1) >> 7; }
    toff[NE] = a;
  }
}

// ---- 2-phase double-buffered K-loop (T3-minimum recipe) ---------------------
// Per K-step: issue STAGE(next tile) -> ds_read+MFMA(current) -> __syncthreads
// (= vmcnt(0)+lgkmcnt(0)+barrier: drains next tile's loads under this step's
// compute; one barrier per K-step). x2-unrolled so buffer indices are static.
// LDS XOR-swizzle: physical 16B-chunk p of row r holds logical chunk p^(r&7);
// staging pre-swizzles the global source; reads XOR on the ds_read side.

#define STG(buf, k0) do{ \
  async16(aptr0 + (k0), &sA[(buf)*TILEE + 0*2048 + tid*8]); \
  async16(aptr1 + (k0), &sA[(buf)*TILEE + 1*2048 + tid*8]); \
  async16(aptr2 + (k0), &sA[(buf)*TILEE + 2*2048 + tid*8]); \
  async16(aptr3 + (k0), &sA[(buf)*TILEE + 3*2048 + tid*8]); \
  _Pragma("unroll") for (int c = 0; c < 4; ++c) \
    async16(bptr + (size_t)(c*32+rowb)*KD + (k0), &sB[(buf)*TILEE + c*2048 + tid*8]); \
  }while(0)

#define CMP(buf) do{ \
  _Pragma("unroll") for (int kk = 0; kk < BK; kk += 32) { \
    int gbase = (kk >> 3) + (lane >> 4); \
    int offE  = ((gbase ^ l7) << 3); \
    bf16x8 af[4], bfr[4]; \
    _Pragma("unroll") for (int i = 0; i < 4; ++i) \
      af[i] = *(const bf16x8*)&sA[(buf)*TILEE + (wm*64 + i*16 + l15)*BK + offE]; \
    _Pragma("unroll") for (int j = 0; j < 4; ++j) \
      bfr[j] = *(const bf16x8*)&sB[(buf)*TILEE + (wn*64 + j*16 + l15)*BK + offE]; \
    _Pragma("unroll") for (int i = 0; i < 4; ++i) \
    _Pragma("unroll") for (int j = 0; j < 4; ++j) \
      acc[i][j] = __builtin_amdgcn_mfma_f32_16x16x32_bf16(af[i], bfr[j], acc[i][j], 0, 0, 0); \
  } }while(0)

#define KLOOP(KD_, NT_) do{ \
  const int KD = KD_; \
  STG(0, 0); \
  __syncthreads(); \
  _Pragma("unroll 1") for (int t = 0; t < (NT_)/2 - 1; ++t) { \
    int k0 = (2*t+1)*BK; \
    STG(1, k0);      CMP(0); __syncthreads(); \
    STG(0, k0+BK);   CMP(1); __syncthreads(); \
  } \
  STG(1, ((NT_)-1)*BK); CMP(0); __syncthreads(); \
  CMP(1); }while(0)

// ---- stage 1: H[slot, DF] = gelu( gather(xb) @ w1[e]^T + b1[e] ) ------------
// grid (DF/128, MAXT); XCD-chunked bijective swizzle (nwg = 32*136, %8==0)

__global__ __launch_bounds__(256, 2) void stage1_k(
    const u16* __restrict__ xb, const u16* __restrict__ w1b,
    const float* __restrict__ b1, const int* __restrict__ bucket,
    const int* __restrict__ counts, const int* __restrict__ toff,
    u16* __restrict__ H)
{
  __shared__ __align__(16) u16 sA[2*TILEE];
  __shared__ __align__(16) u16 sB[2*TILEE];
  __shared__ int sSlot[BM];

  int bid = blockIdx.y * 32 + blockIdx.x;
  int lid = (bid & 7) * ((32 * MAXT) >> 3) + (bid >> 3);
  int fs = lid & 31;          // f-slice fastest: slices of a tile stay adjacent
  int tb = lid >> 5;
  if (tb >= toff[NE]) return;
  int e = 0;
#pragma unroll
  for (int q = 1; q < NE; ++q) if (tb >= toff[q]) e = q;  // last match skips empties
  int ti = tb - toff[e];
  int cnt = counts[e];
  int tid = threadIdx.x;

  if (tid < BM) {
    int r = ti * BM + tid;
    sSlot[tid] = (r < cnt) ? bucket[e * T_TOK + r] : -1;
  }
  __syncthreads();

  int lane = tid & 63, wid = tid >> 6;
  int wm = wid >> 1, wn = wid & 1;
  int l15 = lane & 15;
  int l7  = l15 & 7;
  int rowb = tid >> 3;
  int swz = ((tid & 7) ^ (rowb & 7)) * 8;   // pre-swizzled global chunk offset

  int s0 = sSlot[0*32 + rowb], s1 = sSlot[1*32 + rowb];
  int s2 = sSlot[2*32 + rowb], s3 = sSlot[3*32 + rowb];
  const u16* aptr0 = xb + (size_t)((s0 < 0) ? 0 : (s0 >> 1)) * DM + swz;
  const u16* aptr1 = xb + (size_t)((s1 < 0) ? 0 : (s1 >> 1)) * DM + swz;
  const u16* aptr2 = xb + (size_t)((s2 < 0) ? 0 : (s2 >> 1)) * DM + swz;
  const u16* aptr3 = xb + (size_t)((s3 < 0) ? 0 : (s3 >> 1)) * DM + swz;
  const u16* bptr  = w1b + ((size_t)e * DF + (size_t)fs * 128) * DM + swz;

  f32x4 acc[4][4] = {};
  KLOOP(DM, DM / BK);

  int fbase = fs * 128;
#pragma unroll
  for (int i = 0; i < 4; ++i) {
    int mb = wm * 64 + i * 16 + (lane >> 4) * 4;
#pragma unroll
    for (int j = 0; j < 4; ++j) {
      int col = wn * 64 + j * 16 + l15;
      float bias = b1[e * DF + fbase + col];
#pragma unroll
      for (int r = 0; r < 4; ++r) {
        int slot = sSlot[mb + r];
        if (slot >= 0) {
          float v = acc[i][j][r] + bias;
          H[(size_t)slot * DF + fbase + col] = f2b(fast_gelu(v));
        }
      }
    }
  }
}

// ---- stage 2: out[token] += w * ( gather(H) @ w2[e]^T + b2[e] ) -------------
// grid (DM/128, MAXT), same XCD-chunk swizzle (nwg = 8*136, %8==0)

__global__ __launch_bounds__(256, 2) void stage2_k(
    const u16* __restrict__ H, const u16* __restrict__ w2b,
    const float* __restrict__ b2, const float* __restrict__ wsl,
    const int* __restrict__ bucket, const int* __restrict__ counts,
    const int* __restrict__ toff, float* __restrict__ out)
{
  __shared__ __align__(16) u16 sA[2*TILEE];
  __shared__ __align__(16) u16 sB[2*TILEE];
  __shared__ int sSlot[BM];

  int bid = blockIdx.y * 8 + blockIdx.x;
  int lid = (bid & 7) * MAXT + (bid >> 3);
  int ds = lid & 7;           // d-slice fastest
  int tb = lid >> 3;
  if (tb >= toff[NE]) return;
  int e = 0;
#pragma unroll
  for (int q = 1; q < NE; ++q) if (tb >= toff[q]) e = q;
  int ti = tb - toff[e];
  int cnt = counts[e];
  int tid = threadIdx.x;

  if (tid < BM) {
    int r = ti * BM + tid;
    sSlot[tid] = (r < cnt) ? bucket[e * T_TOK + r] : -1;
  }
  __syncthreads();

  int lane = tid & 63, wid = tid >> 6;
  int wm = wid >> 1, wn = wid & 1;
  int l15 = lane & 15;
  int l7  = l15 & 7;
  int rowb = tid >> 3;
  int swz = ((tid & 7) ^ (rowb & 7)) * 8;

  int s0 = sSlot[0*32 + rowb], s1 = sSlot[1*32 + rowb];
  int s2 = sSlot[2*32 + rowb], s3 = sSlot[3*32 + rowb];
  const u16* aptr0 = H + (size_t)((s0 < 0) ? 0 : s0) * DF + swz;
  const u16* aptr1 = H + (size_t)((s1 < 0) ? 0 : s1) * DF + swz;
  const u16* aptr2 = H + (size_t)((s2 < 0) ? 0 : s2) * DF + swz;
  const u16* aptr3 = H + (size_t)((s3 < 0) ? 0 : s3) * DF + swz;
  const u16* bptr  = w2b + ((size_t)e * DM + (size_t)ds * 128) * DF + swz;

  f32x4 acc[4][4] = {};
  KLOOP(DF, DF / BK);

  int dbase = ds * 128;
#pragma unroll
  for (int i = 0; i < 4; ++i) {
    int mb = wm * 64 + i * 16 + (lane >> 4) * 4;
#pragma unroll
    for (int j = 0; j < 4; ++j) {
      int col = wn * 64 + j * 16 + l15;
      float bias = b2[e * DM + dbase + col];
#pragma unroll
      for (int r = 0; r < 4; ++r) {
        int slot = sSlot[mb + r];
        if (slot >= 0) {
          float v = (acc[i][j][r] + bias) * wsl[slot];
          atomicAdd(&out[(size_t)(slot >> 1) * DM + dbase + col], v);
        }
      }
    }
  }
}

// ---- launch -----------------------------------------------------------------

extern "C" void kernel_launch(void* const* d_in, const int* in_sizes, int n_in,
                              void* d_out, int out_size, void* d_ws, size_t ws_size,
                              hipStream_t stream) {
  const float* x  = (const float*)d_in[0];
  const float* rw = (const float*)d_in[1];
  const float* rb = (const float*)d_in[2];
  const float* w1 = (const float*)d_in[3];
  const float* b1 = (const float*)d_in[4];
  const float* w2 = (const float*)d_in[5];
  const float* b2 = (const float*)d_in[6];
  float* out = (float*)d_out;

  char* ws = (char*)d_ws;
  size_t off = 0;
  auto alloc = [&](size_t bytes) -> void* {
    void* p = ws + off;
    off = (off + bytes + 255) & ~(size_t)255;
    return p;
  };
  u16*   xb     = (u16*)alloc((size_t)T_TOK * DM * 2);        // 16.8 MB
  u16*   w1b    = (u16*)alloc((size_t)NE * DF * DM * 2);      // 67.1 MB
  u16*   w2b    = (u16*)alloc((size_t)NE * DM * DF * 2);      // 67.1 MB
  u16*   H      = (u16*)alloc((size_t)(2 * T_TOK) * DF * 2);  // 134.2 MB
  float* wsl    = (float*)alloc((size_t)(2 * T_TOK) * 4);
  int*   bucket = (int*)alloc((size_t)NE * T_TOK * 4);
  int*   counts = (int*)alloc(256);
  int*   toff   = (int*)alloc(256);

  hipMemsetAsync(counts, 0, NE * sizeof(int), stream);
  hipMemsetAsync(out, 0, (size_t)out_size * sizeof(float), stream);

  router_k<<<T_TOK / 4, 256, 0, stream>>>(x, rw, rb, xb, wsl, bucket, counts);
  cvt_k<<<2048, 256, 0, stream>>>(w1, w1b, (NE * DF * DM) / 4);
  cvt_k<<<2048, 256, 0, stream>>>(w2, w2b, (NE * DM * DF) / 4);
  toff_k<<<1, 64, 0, stream>>>(counts, toff);
  stage1_k<<<dim3(DF / 128, MAXT), 256, 0, stream>>>(xb, w1b, b1, bucket, counts, toff, H);
  stage2_k<<<dim3(DM / 128, MAXT), 256, 0, stream>>>(H, w2b, b2, wsl, bucket, counts, toff, out);
}